// Round 11
// baseline (571.785 us; speedup 1.0000x reference)
//
#include <hip/hip_runtime.h>
#include <hip/hip_fp16.h>

#define NN 50000
#define NE 1600000
#define DD 128
#define NH 9
#define NC 8
#define HCH 72
#define NEG 0.2f
#define NBUCK 196      // ceil(50000/256), 256 dst nodes per bucket
#define NSEG 16        // src segments of 4096 nodes (only 0..12 non-empty)
#define SPAD 17        // padded seg stride in k_scat2 LDS (bank-conflict fix)
#define EPB 8          // edges per thread in k_bin/hcnt
#define BCH (256*EPB)  // 2048 edges per block
#define GEMM_BLKS 196                     // ceil(NN/256)
#define HCNT_BLKS ((NE + BCH - 1) / BCH)  // 782

__device__ __forceinline__ unsigned short f2h(float f) {
  return __half_as_ushort(__float2half_rn(f));
}
__device__ __forceinline__ float h2f(unsigned short u) {
  return __half2float(__ushort_as_half(u));
}
__device__ __forceinline__ float hlo(unsigned u) {
  return __half2float(__ushort_as_half((unsigned short)(u & 0xFFFFu)));
}
__device__ __forceinline__ float hhi(unsigned u) {
  return __half2float(__ushort_as_half((unsigned short)(u >> 16)));
}

struct GP {
  const float* x; const int* ei; const float* W;
  const float* as; const float* ad; const float* b;
  uint4* h2;                // [NN*9] uint4: 8 fp16 channels per (node,head)
  unsigned short* as2;      // [NN*9] fp16 src-attention scores
  float* a_d; float* out;
  int* offs2;               // [NBUCK*256*16+1] per-(node,seg) csr offsets
  int* bcount;              // [NBUCK]
  int* bcursor;             // [NBUCK]
  int* bstart;              // [NBUCK+1]
  unsigned int* pairs; int* csr;
};
struct GT { GP g[3]; };

// Fat kernel: blocks [0,196) do h = x@W with W read via wave-uniform GLOBAL
// loads (scalar-pipe s_load, no LDS); blocks [196, 196+782) do the bucket
// histogram. bcount is zeroed by a hipMemsetAsync before this dispatch.
__global__ __launch_bounds__(256) void k_gemm_hcnt(GT t) {
  const GP G = t.g[blockIdx.z];
  __shared__ int lh[NBUCK];
  const int tid = threadIdx.x;
  if (blockIdx.x >= GEMM_BLKS) {
    // ---- histogram part ----
    const int e0 = (blockIdx.x - GEMM_BLKS) * BCH;
    for (int i = tid; i < NBUCK; i += 256) lh[i] = 0;
    __syncthreads();
    #pragma unroll
    for (int k = 0; k < EPB; ++k) {
      const int e = e0 + k * 256 + tid;
      if (e < NE) atomicAdd(&lh[G.ei[NE + e] >> 8], 1);
    }
    __syncthreads();
    for (int i = tid; i < NBUCK; i += 256) {
      int c = lh[i];
      if (c) atomicAdd(&G.bcount[i], c);
    }
    return;
  }
  // ---- gemm part: one thread per node, 72 channels in registers ----
  const int n = blockIdx.x * 256 + tid;
  if (n >= NN) return;
  float4 acc[18];
  #pragma unroll
  for (int i = 0; i < 18; ++i) acc[i] = make_float4(0.f, 0.f, 0.f, 0.f);
  const float4* __restrict__ x4 = (const float4*)(G.x + (size_t)n * DD);
  const float4* __restrict__ W4 = (const float4*)G.W;   // row k = W4 + k*18

  for (int k4 = 0; k4 < DD / 4; ++k4) {
    const float4 xv = x4[k4];
    const float4* wr = W4 + (size_t)k4 * 4 * (HCH / 4);
    #pragma unroll
    for (int kk = 0; kk < 4; ++kk) {
      const float xk = (kk == 0) ? xv.x : (kk == 1) ? xv.y : (kk == 2) ? xv.z : xv.w;
      #pragma unroll
      for (int c4 = 0; c4 < 18; ++c4) {
        float4 wv = wr[kk * 18 + c4];             // wave-uniform -> s_load
        acc[c4].x = fmaf(xk, wv.x, acc[c4].x);
        acc[c4].y = fmaf(xk, wv.y, acc[c4].y);
        acc[c4].z = fmaf(xk, wv.z, acc[c4].z);
        acc[c4].w = fmaf(xk, wv.w, acc[c4].w);
      }
    }
  }

  #pragma unroll
  for (int hd = 0; hd < NH; ++hd) {
    const float4 a0 = acc[2 * hd];
    const float4 a1 = acc[2 * hd + 1];
    const float4 As0 = *(const float4*)(G.as + hd * NC);
    const float4 As1 = *(const float4*)(G.as + hd * NC + 4);
    const float4 Ad0 = *(const float4*)(G.ad + hd * NC);
    const float4 Ad1 = *(const float4*)(G.ad + hd * NC + 4);
    float ssrc = a0.x*As0.x + a0.y*As0.y + a0.z*As0.z + a0.w*As0.w
               + a1.x*As1.x + a1.y*As1.y + a1.z*As1.z + a1.w*As1.w;
    float sdst = a0.x*Ad0.x + a0.y*Ad0.y + a0.z*Ad0.z + a0.w*Ad0.w
               + a1.x*Ad1.x + a1.y*Ad1.y + a1.z*Ad1.z + a1.w*Ad1.w;
    G.as2[n * NH + hd] = f2h(ssrc);
    G.a_d[n * NH + hd] = sdst;
    uint4 hv;
    hv.x = (unsigned)f2h(a0.x) | ((unsigned)f2h(a0.y) << 16);
    hv.y = (unsigned)f2h(a0.z) | ((unsigned)f2h(a0.w) << 16);
    hv.z = (unsigned)f2h(a1.x) | ((unsigned)f2h(a1.y) << 16);
    hv.w = (unsigned)f2h(a1.z) | ((unsigned)f2h(a1.w) << 16);
    G.h2[(size_t)n * NH + hd] = hv;
  }
}

// scan 196 bucket counts -> bstart / bcursor
__global__ __launch_bounds__(256) void k_scanb(GT t) {
  const GP G = t.g[blockIdx.z];
  __shared__ int s[256];
  const int tid = threadIdx.x;
  int v = (tid < NBUCK) ? G.bcount[tid] : 0;
  s[tid] = v;
  __syncthreads();
  for (int off = 1; off < 256; off <<= 1) {
    int u = (tid >= off) ? s[tid - off] : 0;
    __syncthreads();
    s[tid] += u;
    __syncthreads();
  }
  if (tid < NBUCK) {
    int excl = s[tid] - v;
    G.bcursor[tid] = excl;
    G.bstart[tid] = excl;
  }
  if (tid == 0) G.bstart[NBUCK] = NE;
}

// phase 1: bin edges into 196 dense per-bucket runs of packed (dst_local<<16|src)
__global__ __launch_bounds__(256) void k_bin(GT t) {
  const GP G = t.g[blockIdx.z];
  __shared__ int lh[NBUCK];
  __shared__ int lbase[NBUCK];
  __shared__ int lcur[NBUCK];
  const int tid = threadIdx.x;
  const int e0 = blockIdx.x * BCH;
  for (int i = tid; i < NBUCK; i += 256) lh[i] = 0;
  __syncthreads();
  int dsts[EPB], srcs[EPB];
  #pragma unroll
  for (int k = 0; k < EPB; ++k) {
    const int e = e0 + k * 256 + tid;
    if (e < NE) {
      int dst = G.ei[NE + e];
      srcs[k] = G.ei[e];
      dsts[k] = dst;
      atomicAdd(&lh[dst >> 8], 1);
    } else dsts[k] = -1;
  }
  __syncthreads();
  for (int i = tid; i < NBUCK; i += 256) {
    int c = lh[i];
    lbase[i] = c ? atomicAdd(&G.bcursor[i], c) : 0;
    lcur[i] = 0;
  }
  __syncthreads();
  #pragma unroll
  for (int k = 0; k < EPB; ++k) {
    if (dsts[k] >= 0) {
      int b = dsts[k] >> 8;
      int pos = lbase[b] + atomicAdd(&lcur[b], 1);
      G.pairs[pos] = (unsigned int)srcs[k] | ((unsigned int)(dsts[k] & 255) << 16);
    }
  }
}

// phase 2: one block per bucket. LDS counting sort with key (dst_local,seg):
// emits per-(node,seg) offsets offs2[] and a csr that is dst-major, seg-sorted.
// cnt[] is reused as the cursor array in pass 2 (halves LDS).
__global__ __launch_bounds__(256) void k_scat2(GT t) {
  const GP G = t.g[blockIdx.z];
  const int b = blockIdx.x;
  const int d0 = b << 8;
  __shared__ int cnt[256 * SPAD];   // 17.4 KB (counts, then cursors)
  __shared__ int ssum[256];
  const int tid = threadIdx.x;
  const int estart = G.bstart[b];
  const int eend = G.bstart[b + 1];
  for (int i = tid; i < 256 * SPAD; i += 256) cnt[i] = 0;
  __syncthreads();
  for (int e = estart + tid; e < eend; e += 256) {
    unsigned p = G.pairs[e];
    int key = (int)((p >> 16) * SPAD + ((p & 0xFFFFu) >> 12));
    atomicAdd(&cnt[key], 1);
  }
  __syncthreads();
  // scan: thread t owns keys t*SPAD .. t*SPAD+15 (= dst_local t, all segs)
  int local[NSEG];
  int sum = 0;
  #pragma unroll
  for (int i = 0; i < NSEG; ++i) { local[i] = sum; sum += cnt[tid * SPAD + i]; }
  ssum[tid] = sum;
  __syncthreads();
  int run = sum;
  for (int off = 1; off < 256; off <<= 1) {
    int u = (tid >= off) ? ssum[tid - off] : 0;
    __syncthreads();
    run += u;
    ssum[tid] = run;
    __syncthreads();
  }
  const int texcl = run - sum;
  int* o2 = G.offs2 + ((size_t)d0 << 4);
  #pragma unroll
  for (int i = 0; i < NSEG; ++i) {
    int v = estart + texcl + local[i];
    cnt[tid * SPAD + i] = v;     // counts are dead; reuse as cursors
    o2[tid * NSEG + i] = v;
  }
  if (b == NBUCK - 1 && tid == 0) G.offs2[(size_t)NBUCK * 256 * NSEG] = eend;
  __syncthreads();
  for (int e = estart + tid; e < eend; e += 256) {
    unsigned p = G.pairs[e];
    int key = (int)((p >> 16) * SPAD + ((p & 0xFFFFu) >> 12));
    int pos = atomicAdd(&cnt[key], 1);
    G.csr[pos] = (int)(p & 0xFFFFu);
  }
}

// gather aggregation: thread (dst,head). Barrier every 4 src-segments;
// 8/4/1-tier batched loads for memory-level parallelism. One graph per dispatch.
__global__ __launch_bounds__(256) void k_agg(GP G) {
  const int gid = blockIdx.x * 256 + threadIdx.x;
  const bool active = (gid < NN * NH);
  int n = 0, head = 0;
  if (active) { n = gid / NH; head = gid - n * NH; }
  float denom = 0.f;
  float4 acc0 = make_float4(0.f, 0.f, 0.f, 0.f);
  float4 acc1 = make_float4(0.f, 0.f, 0.f, 0.f);
  float ad_n = 0.f;
  int gb[5] = {0, 0, 0, 0, 0};
  if (active) {
    ad_n = G.a_d[n * NH + head];
    const int* o2 = G.offs2 + ((size_t)n << 4);
    gb[0] = o2[0]; gb[1] = o2[4]; gb[2] = o2[8]; gb[3] = o2[12]; gb[4] = o2[13];
    float sl = h2f(G.as2[n * NH + head]) + ad_n;
    sl = (sl > 0.f) ? sl : NEG * sl;
    float wl = __expf(sl);
    uint4 hs = G.h2[(size_t)n * NH + head];
    denom = wl;
    acc0.x = wl * hlo(hs.x); acc0.y = wl * hhi(hs.x);
    acc0.z = wl * hlo(hs.y); acc0.w = wl * hhi(hs.y);
    acc1.x = wl * hlo(hs.z); acc1.y = wl * hhi(hs.z);
    acc1.z = wl * hlo(hs.w); acc1.w = wl * hhi(hs.w);
  }
  #pragma unroll
  for (int g = 0; g < 4; ++g) {
    int e = gb[g];
    const int en = gb[g + 1];
    for (; e + 8 <= en; e += 8) {
      int s[8];
      #pragma unroll
      for (int i = 0; i < 8; ++i) s[i] = G.csr[e + i];
      unsigned short u[8];
      #pragma unroll
      for (int i = 0; i < 8; ++i) u[i] = G.as2[s[i] * NH + head];
      uint4 v[8];
      #pragma unroll
      for (int i = 0; i < 8; ++i) v[i] = G.h2[(size_t)s[i] * NH + head];
      #pragma unroll
      for (int i = 0; i < 8; ++i) {
        float sc = h2f(u[i]) + ad_n;
        sc = (sc > 0.f) ? sc : NEG * sc;
        float w = __expf(sc);
        denom += w;
        acc0.x = fmaf(w, hlo(v[i].x), acc0.x); acc0.y = fmaf(w, hhi(v[i].x), acc0.y);
        acc0.z = fmaf(w, hlo(v[i].y), acc0.z); acc0.w = fmaf(w, hhi(v[i].y), acc0.w);
        acc1.x = fmaf(w, hlo(v[i].z), acc1.x); acc1.y = fmaf(w, hhi(v[i].z), acc1.y);
        acc1.z = fmaf(w, hlo(v[i].w), acc1.z); acc1.w = fmaf(w, hhi(v[i].w), acc1.w);
      }
    }
    if (e + 4 <= en) {
      int s[4];
      #pragma unroll
      for (int i = 0; i < 4; ++i) s[i] = G.csr[e + i];
      unsigned short u[4];
      #pragma unroll
      for (int i = 0; i < 4; ++i) u[i] = G.as2[s[i] * NH + head];
      uint4 v[4];
      #pragma unroll
      for (int i = 0; i < 4; ++i) v[i] = G.h2[(size_t)s[i] * NH + head];
      #pragma unroll
      for (int i = 0; i < 4; ++i) {
        float sc = h2f(u[i]) + ad_n;
        sc = (sc > 0.f) ? sc : NEG * sc;
        float w = __expf(sc);
        denom += w;
        acc0.x = fmaf(w, hlo(v[i].x), acc0.x); acc0.y = fmaf(w, hhi(v[i].x), acc0.y);
        acc0.z = fmaf(w, hlo(v[i].y), acc0.z); acc0.w = fmaf(w, hhi(v[i].y), acc0.w);
        acc1.x = fmaf(w, hlo(v[i].z), acc1.x); acc1.y = fmaf(w, hhi(v[i].z), acc1.y);
        acc1.z = fmaf(w, hlo(v[i].w), acc1.z); acc1.w = fmaf(w, hhi(v[i].w), acc1.w);
      }
      e += 4;
    }
    for (; e < en; ++e) {
      int src = G.csr[e];
      float sc = h2f(G.as2[src * NH + head]) + ad_n;
      sc = (sc > 0.f) ? sc : NEG * sc;
      float w = __expf(sc);
      uint4 hv = G.h2[(size_t)src * NH + head];
      denom += w;
      acc0.x = fmaf(w, hlo(hv.x), acc0.x); acc0.y = fmaf(w, hhi(hv.x), acc0.y);
      acc0.z = fmaf(w, hlo(hv.y), acc0.z); acc0.w = fmaf(w, hhi(hv.y), acc0.w);
      acc1.x = fmaf(w, hlo(hv.z), acc1.x); acc1.y = fmaf(w, hhi(hv.z), acc1.y);
      acc1.z = fmaf(w, hlo(hv.w), acc1.z); acc1.w = fmaf(w, hhi(hv.w), acc1.w);
    }
    __syncthreads();
  }
  if (!active) return;
  float inv = 1.f / (denom + 1e-16f);
  const float* bp = G.b + head * NC;
  float4 o0, o1;
  o0.x = acc0.x * inv + bp[0]; o0.y = acc0.y * inv + bp[1];
  o0.z = acc0.z * inv + bp[2]; o0.w = acc0.w * inv + bp[3];
  o1.x = acc1.x * inv + bp[4]; o1.y = acc1.y * inv + bp[5];
  o1.z = acc1.z * inv + bp[6]; o1.w = acc1.w * inv + bp[7];
  float4* op = (float4*)(G.out + (size_t)n * HCH + head * NC);
  op[0] = o0; op[1] = o1;
}

// relu(concat) @ fnn_W + fnn_b -> softmax(2). One wave per node.
__global__ __launch_bounds__(256) void k_fnn(const float* __restrict__ o1,
                                             const float* __restrict__ o2,
                                             const float* __restrict__ o3,
                                             const float* __restrict__ fw,
                                             const float* __restrict__ fb,
                                             float* __restrict__ out) {
  const int tid = blockIdx.x * 256 + threadIdx.x;
  const int n = tid >> 6;
  const int lane = tid & 63;
  if (n >= NN) return;
  float acc0 = 0.f, acc1 = 0.f;
  for (int j = lane; j < 3 * HCH; j += 64) {
    const int g = j / HCH;
    const int c = j - g * HCH;
    const float* og = (g == 0) ? o1 : (g == 1) ? o2 : o3;
    float v = og[(size_t)n * HCH + c];
    v = v > 0.f ? v : 0.f;
    acc0 = fmaf(v, fw[2 * j], acc0);
    acc1 = fmaf(v, fw[2 * j + 1], acc1);
  }
  #pragma unroll
  for (int off = 32; off > 0; off >>= 1) {
    acc0 += __shfl_down(acc0, off, 64);
    acc1 += __shfl_down(acc1, off, 64);
  }
  if (lane == 0) {
    float l0 = acc0 + fb[0], l1 = acc1 + fb[1];
    float m = fmaxf(l0, l1);
    float e0 = __expf(l0 - m), e1 = __expf(l1 - m);
    float inv = 1.f / (e0 + e1);
    out[(size_t)n * 2] = e0 * inv;
    out[(size_t)n * 2 + 1] = e1 * inv;
  }
}

extern "C" void kernel_launch(void* const* d_in, const int* in_sizes, int n_in,
                              void* d_out, int out_size, void* d_ws, size_t ws_size,
                              hipStream_t stream) {
  (void)in_sizes; (void)n_in; (void)out_size; (void)ws_size;
  GT t;
  char* w = (char*)d_ws;
  size_t off = 0;
  auto carve = [&](size_t bytes) -> void* {
    void* p = w + off;
    off = (off + bytes + 255) & ~(size_t)255;
    return p;
  };
  int* bc_all = (int*)carve(3 * 256 * 4);   // 3 graphs' bcount, contiguous
  for (int g = 0; g < 3; ++g) {
    GP& G = t.g[g];
    G.x  = (const float*)d_in[6 * g + 0];
    G.ei = (const int*)d_in[6 * g + 1];     // harness stores int64 inputs as int32
    G.W  = (const float*)d_in[6 * g + 2];
    G.as = (const float*)d_in[6 * g + 3];
    G.ad = (const float*)d_in[6 * g + 4];
    G.b  = (const float*)d_in[6 * g + 5];
    G.bcount = bc_all + g * 256;
    G.h2   = (uint4*)carve((size_t)NN * NH * 16);
    G.as2  = (unsigned short*)carve((size_t)NN * NH * 2);
    G.a_d  = (float*)carve((size_t)NN * NH * 4);
    G.out  = (float*)carve((size_t)NN * HCH * 4);
    G.offs2 = (int*)carve(((size_t)NBUCK * 256 * NSEG + 1) * 4);
    G.bcursor = (int*)carve((size_t)NBUCK * 4);
    G.bstart  = (int*)carve((size_t)(NBUCK + 1) * 4);
    G.pairs = (unsigned int*)carve((size_t)NE * 4);
    G.csr  = (int*)carve((size_t)NE * 4);
  }
  const float* fw = (const float*)d_in[18];
  const float* fb = (const float*)d_in[19];
  float* outp = (float*)d_out;

  dim3 b256(256, 1, 1);
  hipMemsetAsync(bc_all, 0, 3 * 256 * 4, stream);
  k_gemm_hcnt<<<dim3(GEMM_BLKS + HCNT_BLKS, 1, 3), b256, 0, stream>>>(t);
  k_scanb    <<<dim3(1, 1, 3), b256, 0, stream>>>(t);
  k_bin      <<<dim3(HCNT_BLKS, 1, 3), b256, 0, stream>>>(t);
  k_scat2    <<<dim3(NBUCK, 1, 3), b256, 0, stream>>>(t);
  for (int g = 0; g < 3; ++g)
    k_agg    <<<dim3((NN * NH + 255) / 256, 1, 1), b256, 0, stream>>>(t.g[g]);
  k_fnn      <<<(NN * 64 + 255) / 256, b256, 0, stream>>>(t.g[0].out, t.g[1].out, t.g[2].out, fw, fb, outp);
}

// Round 12
// 541.177 us; speedup vs baseline: 1.0566x; 1.0566x over previous
//
#include <hip/hip_runtime.h>
#include <hip/hip_fp16.h>

#define NN 50000
#define NE 1600000
#define DD 128
#define NH 9
#define NC 8
#define HCH 72
#define NEG 0.2f
#define NBUCK 196      // ceil(50000/256), 256 dst nodes per bucket
#define NSEG 16        // src segments of 4096 nodes (only 0..12 non-empty)
#define SPAD 17        // padded seg stride in k_scat2 LDS (bank-conflict fix)
#define EPB 8          // edges per thread in k_bin/hcnt
#define BCH (256*EPB)  // 2048 edges per block
#define GEMM_BLKS 196                     // ceil(NN/256)
#define HCNT_BLKS ((NE + BCH - 1) / BCH)  // 782

__device__ __forceinline__ unsigned short f2h(float f) {
  return __half_as_ushort(__float2half_rn(f));
}
__device__ __forceinline__ float h2f(unsigned short u) {
  return __half2float(__ushort_as_half(u));
}
__device__ __forceinline__ float hlo(unsigned u) {
  return __half2float(__ushort_as_half((unsigned short)(u & 0xFFFFu)));
}
__device__ __forceinline__ float hhi(unsigned u) {
  return __half2float(__ushort_as_half((unsigned short)(u >> 16)));
}

struct GP {
  const float* x; const int* ei; const float* W;
  const float* as; const float* ad; const float* b;
  uint4* h2;                // [NN*9] uint4: 8 fp16 channels per (node,head)
  unsigned short* as2;      // [NN*9] fp16 src-attention scores
  float* a_d; float* out;
  int* offs2;               // [NBUCK*256*16+1] per-(node,seg) csr offsets
  int* bcount;              // [NBUCK]
  int* bcursor;             // [NBUCK]
  int* bstart;              // [NBUCK+1]
  unsigned int* pairs; int* csr;
};
struct GT { GP g[3]; };

// Fat kernel: blocks [0,196) do h = x@W with W staged in LDS (proven R10 path);
// blocks [196,978) do the bucket histogram. bcount zeroed via hipMemsetAsync.
__global__ __launch_bounds__(256) void k_gemm_hcnt(GT t) {
  const GP G = t.g[blockIdx.z];
  __shared__ float Wl[DD * HCH];   // 36 KB
  __shared__ int lh[NBUCK];
  const int tid = threadIdx.x;
  if (blockIdx.x >= GEMM_BLKS) {
    // ---- histogram part ----
    const int e0 = (blockIdx.x - GEMM_BLKS) * BCH;
    for (int i = tid; i < NBUCK; i += 256) lh[i] = 0;
    __syncthreads();
    #pragma unroll
    for (int k = 0; k < EPB; ++k) {
      const int e = e0 + k * 256 + tid;
      if (e < NE) atomicAdd(&lh[G.ei[NE + e] >> 8], 1);
    }
    __syncthreads();
    for (int i = tid; i < NBUCK; i += 256) {
      int c = lh[i];
      if (c) atomicAdd(&G.bcount[i], c);
    }
    return;
  }
  // ---- gemm part: one thread per node, 72 channels in registers ----
  {
    const float4* Wg = (const float4*)G.W;
    float4* Wd = (float4*)Wl;
    #pragma unroll
    for (int i = 0; i < 9; ++i) Wd[tid + 256 * i] = Wg[tid + 256 * i];  // 2304 = 256*9
  }
  const int n = blockIdx.x * 256 + tid;
  __syncthreads();
  if (n >= NN) return;

  float4 acc[18];
  #pragma unroll
  for (int i = 0; i < 18; ++i) acc[i] = make_float4(0.f, 0.f, 0.f, 0.f);
  const float4* x4 = (const float4*)(G.x + (size_t)n * DD);

  for (int k4 = 0; k4 < DD / 4; ++k4) {
    const float4 xv = x4[k4];
    const float* w0 = &Wl[(k4 * 4) * HCH];
    #pragma unroll
    for (int kk = 0; kk < 4; ++kk) {
      const float xk = (kk == 0) ? xv.x : (kk == 1) ? xv.y : (kk == 2) ? xv.z : xv.w;
      const float4* wr = (const float4*)(w0 + kk * HCH);
      #pragma unroll
      for (int c4 = 0; c4 < 18; ++c4) {
        float4 wv = wr[c4];                       // wave-uniform LDS broadcast
        acc[c4].x = fmaf(xk, wv.x, acc[c4].x);
        acc[c4].y = fmaf(xk, wv.y, acc[c4].y);
        acc[c4].z = fmaf(xk, wv.z, acc[c4].z);
        acc[c4].w = fmaf(xk, wv.w, acc[c4].w);
      }
    }
  }

  #pragma unroll
  for (int hd = 0; hd < NH; ++hd) {
    const float4 a0 = acc[2 * hd];
    const float4 a1 = acc[2 * hd + 1];
    const float4 As0 = *(const float4*)(G.as + hd * NC);
    const float4 As1 = *(const float4*)(G.as + hd * NC + 4);
    const float4 Ad0 = *(const float4*)(G.ad + hd * NC);
    const float4 Ad1 = *(const float4*)(G.ad + hd * NC + 4);
    float ssrc = a0.x*As0.x + a0.y*As0.y + a0.z*As0.z + a0.w*As0.w
               + a1.x*As1.x + a1.y*As1.y + a1.z*As1.z + a1.w*As1.w;
    float sdst = a0.x*Ad0.x + a0.y*Ad0.y + a0.z*Ad0.z + a0.w*Ad0.w
               + a1.x*Ad1.x + a1.y*Ad1.y + a1.z*Ad1.z + a1.w*Ad1.w;
    G.as2[n * NH + hd] = f2h(ssrc);
    G.a_d[n * NH + hd] = sdst;
    uint4 hv;
    hv.x = (unsigned)f2h(a0.x) | ((unsigned)f2h(a0.y) << 16);
    hv.y = (unsigned)f2h(a0.z) | ((unsigned)f2h(a0.w) << 16);
    hv.z = (unsigned)f2h(a1.x) | ((unsigned)f2h(a1.y) << 16);
    hv.w = (unsigned)f2h(a1.z) | ((unsigned)f2h(a1.w) << 16);
    G.h2[(size_t)n * NH + hd] = hv;
  }
}

// scan 196 bucket counts -> bstart / bcursor
__global__ __launch_bounds__(256) void k_scanb(GT t) {
  const GP G = t.g[blockIdx.z];
  __shared__ int s[256];
  const int tid = threadIdx.x;
  int v = (tid < NBUCK) ? G.bcount[tid] : 0;
  s[tid] = v;
  __syncthreads();
  for (int off = 1; off < 256; off <<= 1) {
    int u = (tid >= off) ? s[tid - off] : 0;
    __syncthreads();
    s[tid] += u;
    __syncthreads();
  }
  if (tid < NBUCK) {
    int excl = s[tid] - v;
    G.bcursor[tid] = excl;
    G.bstart[tid] = excl;
  }
  if (tid == 0) G.bstart[NBUCK] = NE;
}

// phase 1: bin edges into 196 dense per-bucket runs of packed (dst_local<<16|src)
__global__ __launch_bounds__(256) void k_bin(GT t) {
  const GP G = t.g[blockIdx.z];
  __shared__ int lh[NBUCK];
  __shared__ int lbase[NBUCK];
  __shared__ int lcur[NBUCK];
  const int tid = threadIdx.x;
  const int e0 = blockIdx.x * BCH;
  for (int i = tid; i < NBUCK; i += 256) lh[i] = 0;
  __syncthreads();
  int dsts[EPB], srcs[EPB];
  #pragma unroll
  for (int k = 0; k < EPB; ++k) {
    const int e = e0 + k * 256 + tid;
    if (e < NE) {
      int dst = G.ei[NE + e];
      srcs[k] = G.ei[e];
      dsts[k] = dst;
      atomicAdd(&lh[dst >> 8], 1);
    } else dsts[k] = -1;
  }
  __syncthreads();
  for (int i = tid; i < NBUCK; i += 256) {
    int c = lh[i];
    lbase[i] = c ? atomicAdd(&G.bcursor[i], c) : 0;
    lcur[i] = 0;
  }
  __syncthreads();
  #pragma unroll
  for (int k = 0; k < EPB; ++k) {
    if (dsts[k] >= 0) {
      int b = dsts[k] >> 8;
      int pos = lbase[b] + atomicAdd(&lcur[b], 1);
      G.pairs[pos] = (unsigned int)srcs[k] | ((unsigned int)(dsts[k] & 255) << 16);
    }
  }
}

// phase 2: one block per bucket. LDS counting sort with key (dst_local,seg):
// emits per-(node,seg) offsets offs2[] and a csr that is dst-major, seg-sorted.
// cnt[] reused as the cursor array in pass 2 (halves LDS).
__global__ __launch_bounds__(256) void k_scat2(GT t) {
  const GP G = t.g[blockIdx.z];
  const int b = blockIdx.x;
  const int d0 = b << 8;
  __shared__ int cnt[256 * SPAD];   // 17.4 KB (counts, then cursors)
  __shared__ int ssum[256];
  const int tid = threadIdx.x;
  const int estart = G.bstart[b];
  const int eend = G.bstart[b + 1];
  for (int i = tid; i < 256 * SPAD; i += 256) cnt[i] = 0;
  __syncthreads();
  for (int e = estart + tid; e < eend; e += 256) {
    unsigned p = G.pairs[e];
    int key = (int)((p >> 16) * SPAD + ((p & 0xFFFFu) >> 12));
    atomicAdd(&cnt[key], 1);
  }
  __syncthreads();
  // scan: thread t owns keys t*SPAD .. t*SPAD+15 (= dst_local t, all segs)
  int local[NSEG];
  int sum = 0;
  #pragma unroll
  for (int i = 0; i < NSEG; ++i) { local[i] = sum; sum += cnt[tid * SPAD + i]; }
  ssum[tid] = sum;
  __syncthreads();
  int run = sum;
  for (int off = 1; off < 256; off <<= 1) {
    int u = (tid >= off) ? ssum[tid - off] : 0;
    __syncthreads();
    run += u;
    ssum[tid] = run;
    __syncthreads();
  }
  const int texcl = run - sum;
  int* o2 = G.offs2 + ((size_t)d0 << 4);
  #pragma unroll
  for (int i = 0; i < NSEG; ++i) {
    int v = estart + texcl + local[i];
    cnt[tid * SPAD + i] = v;     // counts are dead; reuse as cursors
    o2[tid * NSEG + i] = v;
  }
  if (b == NBUCK - 1 && tid == 0) G.offs2[(size_t)NBUCK * 256 * NSEG] = eend;
  __syncthreads();
  for (int e = estart + tid; e < eend; e += 256) {
    unsigned p = G.pairs[e];
    int key = (int)((p >> 16) * SPAD + ((p & 0xFFFFu) >> 12));
    int pos = atomicAdd(&cnt[key], 1);
    G.csr[pos] = (int)(p & 0xFFFFu);
  }
}

// gather aggregation: thread (dst,head). Barrier every 4 src-segments;
// 8/4/1-tier batched loads for memory-level parallelism. One graph per dispatch.
__global__ __launch_bounds__(256) void k_agg(GP G) {
  const int gid = blockIdx.x * 256 + threadIdx.x;
  const bool active = (gid < NN * NH);
  int n = 0, head = 0;
  if (active) { n = gid / NH; head = gid - n * NH; }
  float denom = 0.f;
  float4 acc0 = make_float4(0.f, 0.f, 0.f, 0.f);
  float4 acc1 = make_float4(0.f, 0.f, 0.f, 0.f);
  float ad_n = 0.f;
  int gb[5] = {0, 0, 0, 0, 0};
  if (active) {
    ad_n = G.a_d[n * NH + head];
    const int* o2 = G.offs2 + ((size_t)n << 4);
    gb[0] = o2[0]; gb[1] = o2[4]; gb[2] = o2[8]; gb[3] = o2[12]; gb[4] = o2[13];
    float sl = h2f(G.as2[n * NH + head]) + ad_n;
    sl = (sl > 0.f) ? sl : NEG * sl;
    float wl = __expf(sl);
    uint4 hs = G.h2[(size_t)n * NH + head];
    denom = wl;
    acc0.x = wl * hlo(hs.x); acc0.y = wl * hhi(hs.x);
    acc0.z = wl * hlo(hs.y); acc0.w = wl * hhi(hs.y);
    acc1.x = wl * hlo(hs.z); acc1.y = wl * hhi(hs.z);
    acc1.z = wl * hlo(hs.w); acc1.w = wl * hhi(hs.w);
  }
  #pragma unroll
  for (int g = 0; g < 4; ++g) {
    int e = gb[g];
    const int en = gb[g + 1];
    for (; e + 8 <= en; e += 8) {
      int s[8];
      #pragma unroll
      for (int i = 0; i < 8; ++i) s[i] = G.csr[e + i];
      unsigned short u[8];
      #pragma unroll
      for (int i = 0; i < 8; ++i) u[i] = G.as2[s[i] * NH + head];
      uint4 v[8];
      #pragma unroll
      for (int i = 0; i < 8; ++i) v[i] = G.h2[(size_t)s[i] * NH + head];
      #pragma unroll
      for (int i = 0; i < 8; ++i) {
        float sc = h2f(u[i]) + ad_n;
        sc = (sc > 0.f) ? sc : NEG * sc;
        float w = __expf(sc);
        denom += w;
        acc0.x = fmaf(w, hlo(v[i].x), acc0.x); acc0.y = fmaf(w, hhi(v[i].x), acc0.y);
        acc0.z = fmaf(w, hlo(v[i].y), acc0.z); acc0.w = fmaf(w, hhi(v[i].y), acc0.w);
        acc1.x = fmaf(w, hlo(v[i].z), acc1.x); acc1.y = fmaf(w, hhi(v[i].z), acc1.y);
        acc1.z = fmaf(w, hlo(v[i].w), acc1.z); acc1.w = fmaf(w, hhi(v[i].w), acc1.w);
      }
    }
    if (e + 4 <= en) {
      int s[4];
      #pragma unroll
      for (int i = 0; i < 4; ++i) s[i] = G.csr[e + i];
      unsigned short u[4];
      #pragma unroll
      for (int i = 0; i < 4; ++i) u[i] = G.as2[s[i] * NH + head];
      uint4 v[4];
      #pragma unroll
      for (int i = 0; i < 4; ++i) v[i] = G.h2[(size_t)s[i] * NH + head];
      #pragma unroll
      for (int i = 0; i < 4; ++i) {
        float sc = h2f(u[i]) + ad_n;
        sc = (sc > 0.f) ? sc : NEG * sc;
        float w = __expf(sc);
        denom += w;
        acc0.x = fmaf(w, hlo(v[i].x), acc0.x); acc0.y = fmaf(w, hhi(v[i].x), acc0.y);
        acc0.z = fmaf(w, hlo(v[i].y), acc0.z); acc0.w = fmaf(w, hhi(v[i].y), acc0.w);
        acc1.x = fmaf(w, hlo(v[i].z), acc1.x); acc1.y = fmaf(w, hhi(v[i].z), acc1.y);
        acc1.z = fmaf(w, hlo(v[i].w), acc1.z); acc1.w = fmaf(w, hhi(v[i].w), acc1.w);
      }
      e += 4;
    }
    for (; e < en; ++e) {
      int src = G.csr[e];
      float sc = h2f(G.as2[src * NH + head]) + ad_n;
      sc = (sc > 0.f) ? sc : NEG * sc;
      float w = __expf(sc);
      uint4 hv = G.h2[(size_t)src * NH + head];
      denom += w;
      acc0.x = fmaf(w, hlo(hv.x), acc0.x); acc0.y = fmaf(w, hhi(hv.x), acc0.y);
      acc0.z = fmaf(w, hlo(hv.y), acc0.z); acc0.w = fmaf(w, hhi(hv.y), acc0.w);
      acc1.x = fmaf(w, hlo(hv.z), acc1.x); acc1.y = fmaf(w, hhi(hv.z), acc1.y);
      acc1.z = fmaf(w, hlo(hv.w), acc1.z); acc1.w = fmaf(w, hhi(hv.w), acc1.w);
    }
    __syncthreads();
  }
  if (!active) return;
  float inv = 1.f / (denom + 1e-16f);
  const float* bp = G.b + head * NC;
  float4 o0, o1;
  o0.x = acc0.x * inv + bp[0]; o0.y = acc0.y * inv + bp[1];
  o0.z = acc0.z * inv + bp[2]; o0.w = acc0.w * inv + bp[3];
  o1.x = acc1.x * inv + bp[4]; o1.y = acc1.y * inv + bp[5];
  o1.z = acc1.z * inv + bp[6]; o1.w = acc1.w * inv + bp[7];
  float4* op = (float4*)(G.out + (size_t)n * HCH + head * NC);
  op[0] = o0; op[1] = o1;
}

// relu(concat) @ fnn_W + fnn_b -> softmax(2). One wave per node.
__global__ __launch_bounds__(256) void k_fnn(const float* __restrict__ o1,
                                             const float* __restrict__ o2,
                                             const float* __restrict__ o3,
                                             const float* __restrict__ fw,
                                             const float* __restrict__ fb,
                                             float* __restrict__ out) {
  const int tid = blockIdx.x * 256 + threadIdx.x;
  const int n = tid >> 6;
  const int lane = tid & 63;
  if (n >= NN) return;
  float acc0 = 0.f, acc1 = 0.f;
  for (int j = lane; j < 3 * HCH; j += 64) {
    const int g = j / HCH;
    const int c = j - g * HCH;
    const float* og = (g == 0) ? o1 : (g == 1) ? o2 : o3;
    float v = og[(size_t)n * HCH + c];
    v = v > 0.f ? v : 0.f;
    acc0 = fmaf(v, fw[2 * j], acc0);
    acc1 = fmaf(v, fw[2 * j + 1], acc1);
  }
  #pragma unroll
  for (int off = 32; off > 0; off >>= 1) {
    acc0 += __shfl_down(acc0, off, 64);
    acc1 += __shfl_down(acc1, off, 64);
  }
  if (lane == 0) {
    float l0 = acc0 + fb[0], l1 = acc1 + fb[1];
    float m = fmaxf(l0, l1);
    float e0 = __expf(l0 - m), e1 = __expf(l1 - m);
    float inv = 1.f / (e0 + e1);
    out[(size_t)n * 2] = e0 * inv;
    out[(size_t)n * 2 + 1] = e1 * inv;
  }
}

extern "C" void kernel_launch(void* const* d_in, const int* in_sizes, int n_in,
                              void* d_out, int out_size, void* d_ws, size_t ws_size,
                              hipStream_t stream) {
  (void)in_sizes; (void)n_in; (void)out_size; (void)ws_size;
  GT t;
  char* w = (char*)d_ws;
  size_t off = 0;
  auto carve = [&](size_t bytes) -> void* {
    void* p = w + off;
    off = (off + bytes + 255) & ~(size_t)255;
    return p;
  };
  int* bc_all = (int*)carve(3 * 256 * 4);   // 3 graphs' bcount, contiguous
  for (int g = 0; g < 3; ++g) {
    GP& G = t.g[g];
    G.x  = (const float*)d_in[6 * g + 0];
    G.ei = (const int*)d_in[6 * g + 1];     // harness stores int64 inputs as int32
    G.W  = (const float*)d_in[6 * g + 2];
    G.as = (const float*)d_in[6 * g + 3];
    G.ad = (const float*)d_in[6 * g + 4];
    G.b  = (const float*)d_in[6 * g + 5];
    G.bcount = bc_all + g * 256;
    G.h2   = (uint4*)carve((size_t)NN * NH * 16);
    G.as2  = (unsigned short*)carve((size_t)NN * NH * 2);
    G.a_d  = (float*)carve((size_t)NN * NH * 4);
    G.out  = (float*)carve((size_t)NN * HCH * 4);
    G.offs2 = (int*)carve(((size_t)NBUCK * 256 * NSEG + 1) * 4);
    G.bcursor = (int*)carve((size_t)NBUCK * 4);
    G.bstart  = (int*)carve((size_t)(NBUCK + 1) * 4);
    G.pairs = (unsigned int*)carve((size_t)NE * 4);
    G.csr  = (int*)carve((size_t)NE * 4);
  }
  const float* fw = (const float*)d_in[18];
  const float* fb = (const float*)d_in[19];
  float* outp = (float*)d_out;

  dim3 b256(256, 1, 1);
  hipMemsetAsync(bc_all, 0, 3 * 256 * 4, stream);
  k_gemm_hcnt<<<dim3(GEMM_BLKS + HCNT_BLKS, 1, 3), b256, 0, stream>>>(t);
  k_scanb    <<<dim3(1, 1, 3), b256, 0, stream>>>(t);
  k_bin      <<<dim3(HCNT_BLKS, 1, 3), b256, 0, stream>>>(t);
  k_scat2    <<<dim3(NBUCK, 1, 3), b256, 0, stream>>>(t);
  for (int g = 0; g < 3; ++g)
    k_agg    <<<dim3((NN * NH + 255) / 256, 1, 1), b256, 0, stream>>>(t.g[g]);
  k_fnn      <<<(NN * 64 + 255) / 256, b256, 0, stream>>>(t.g[0].out, t.g[1].out, t.g[2].out, fw, fb, outp);
}

// Round 13
// 455.763 us; speedup vs baseline: 1.2546x; 1.1874x over previous
//
#include <hip/hip_runtime.h>
#include <hip/hip_fp16.h>

#define NN 50000
#define NE 1600000
#define DD 128
#define NH 9
#define NC 8
#define HCH 72
#define NEG 0.2f
#define NBUCK 196      // ceil(50000/256), 256 dst nodes per bucket
#define NSEG 16        // src segments of 4096 nodes (only 0..12 non-empty)
#define SPAD 17        // padded seg stride in k_scat2 LDS (bank-conflict fix)
#define EPB 8          // edges per thread in bin part
#define BCH (256*EPB)  // 2048 edges per bin block
#define BSTRIDE 10240  // fixed per-bucket capacity (mean 8192, sigma 90 -> +22 sigma)
#define GEMMB 586      // ceil(NN*3/256) gemm blocks
#define BINB ((NE + BCH - 1) / BCH)  // 782 bin blocks

__device__ __forceinline__ unsigned short f2h(float f) {
  return __half_as_ushort(__float2half_rn(f));
}
__device__ __forceinline__ float h2f(unsigned short u) {
  return __half2float(__ushort_as_half(u));
}
__device__ __forceinline__ float hlo(unsigned u) {
  return __half2float(__ushort_as_half((unsigned short)(u & 0xFFFFu)));
}
__device__ __forceinline__ float hhi(unsigned u) {
  return __half2float(__ushort_as_half((unsigned short)(u >> 16)));
}

struct GP {
  const float* x; const int* ei; const float* W;
  const float* as; const float* ad; const float* b;
  uint4* h2;                // [NN*9] uint4: 8 fp16 channels per (node,head)
  unsigned short* as2;      // [NN*9] fp16 src-attention scores
  float* a_d; float* out;
  int* offs2;               // [NBUCK*256*16] per-(node,seg) absolute csr offsets
  int* bcursor;             // [NBUCK] bucket fill counts (atomic)
  unsigned int* pairs;      // [NBUCK*BSTRIDE] strided bucket runs
  int* csr;                 // [NBUCK*BSTRIDE]
};
struct GT { GP g[3]; };

// Fat kernel. Blocks [0,GEMMB): h = x@W, one thread per (node, head-triple),
// 24 channels in registers, W in LDS (6 contiguous b128 broadcasts per k).
// Blocks [GEMMB, GEMMB+BINB): bin edges into fixed-stride bucket runs of
// packed (dst_local<<16|src), reserving space via atomicAdd on bcursor
// (zeroed by hipMemsetAsync). No histogram/scan stages needed.
__global__ __launch_bounds__(256) void k_gemm_bin(GT t) {
  const GP G = t.g[blockIdx.z];
  __shared__ float Wl[DD * HCH];   // 36 KB
  const int tid = threadIdx.x;

  if (blockIdx.x >= GEMMB) {
    // ---- bin part (aliases Wl as int scratch) ----
    int* lh    = (int*)Wl;         // 256 ints
    int* lbase = lh + 256;
    int* lcur  = lbase + 256;
    const int e0 = (blockIdx.x - GEMMB) * BCH;
    for (int i = tid; i < NBUCK; i += 256) lh[i] = 0;
    __syncthreads();
    int dsts[EPB], srcs[EPB];
    #pragma unroll
    for (int k = 0; k < EPB; ++k) {
      const int e = e0 + k * 256 + tid;
      if (e < NE) {
        dsts[k] = G.ei[NE + e];
        srcs[k] = G.ei[e];
        atomicAdd(&lh[dsts[k] >> 8], 1);
      } else dsts[k] = -1;
    }
    __syncthreads();
    for (int i = tid; i < NBUCK; i += 256) {
      int c = lh[i];
      lbase[i] = c ? atomicAdd(&G.bcursor[i], c) : 0;
      lcur[i] = 0;
    }
    __syncthreads();
    #pragma unroll
    for (int k = 0; k < EPB; ++k) {
      if (dsts[k] >= 0) {
        int b = dsts[k] >> 8;
        int pos = lbase[b] + atomicAdd(&lcur[b], 1);
        if (pos < BSTRIDE)   // overflow guard (+22 sigma, effectively never)
          G.pairs[(size_t)b * BSTRIDE + pos] =
              (unsigned)srcs[k] | ((unsigned)(dsts[k] & 255) << 16);
      }
    }
    return;
  }

  // ---- gemm part ----
  {
    const float4* Wg = (const float4*)G.W;
    float4* Wd = (float4*)Wl;
    #pragma unroll
    for (int i = 0; i < 9; ++i) Wd[tid + 256 * i] = Wg[tid + 256 * i];  // 2304
  }
  const int gid = blockIdx.x * 256 + tid;
  __syncthreads();
  if (gid >= NN * 3) return;
  const int n  = gid / 3;
  const int g3 = gid - n * 3;            // heads 3*g3 .. 3*g3+2
  float4 acc[6];
  #pragma unroll
  for (int i = 0; i < 6; ++i) acc[i] = make_float4(0.f, 0.f, 0.f, 0.f);
  const float4* x4 = (const float4*)(G.x + (size_t)n * DD);
  const float* wb = Wl + g3 * 24;

  for (int k4 = 0; k4 < DD / 4; ++k4) {
    const float4 xv = x4[k4];
    #pragma unroll
    for (int kk = 0; kk < 4; ++kk) {
      const float xk = (kk == 0) ? xv.x : (kk == 1) ? xv.y : (kk == 2) ? xv.z : xv.w;
      const float4* wr = (const float4*)(wb + (k4 * 4 + kk) * HCH);
      #pragma unroll
      for (int c = 0; c < 6; ++c) {
        float4 wv = wr[c];     // 3 distinct lane-addresses, banks {0,24,16}
        acc[c].x = fmaf(xk, wv.x, acc[c].x);
        acc[c].y = fmaf(xk, wv.y, acc[c].y);
        acc[c].z = fmaf(xk, wv.z, acc[c].z);
        acc[c].w = fmaf(xk, wv.w, acc[c].w);
      }
    }
  }

  #pragma unroll
  for (int j = 0; j < 3; ++j) {
    const int hd = 3 * g3 + j;
    const float4 a0 = acc[2 * j];
    const float4 a1 = acc[2 * j + 1];
    const float4 As0 = *(const float4*)(G.as + hd * NC);
    const float4 As1 = *(const float4*)(G.as + hd * NC + 4);
    const float4 Ad0 = *(const float4*)(G.ad + hd * NC);
    const float4 Ad1 = *(const float4*)(G.ad + hd * NC + 4);
    float ssrc = a0.x*As0.x + a0.y*As0.y + a0.z*As0.z + a0.w*As0.w
               + a1.x*As1.x + a1.y*As1.y + a1.z*As1.z + a1.w*As1.w;
    float sdst = a0.x*Ad0.x + a0.y*Ad0.y + a0.z*Ad0.z + a0.w*Ad0.w
               + a1.x*Ad1.x + a1.y*Ad1.y + a1.z*Ad1.z + a1.w*Ad1.w;
    G.as2[n * NH + hd] = f2h(ssrc);
    G.a_d[n * NH + hd] = sdst;
    uint4 hv;
    hv.x = (unsigned)f2h(a0.x) | ((unsigned)f2h(a0.y) << 16);
    hv.y = (unsigned)f2h(a0.z) | ((unsigned)f2h(a0.w) << 16);
    hv.z = (unsigned)f2h(a1.x) | ((unsigned)f2h(a1.y) << 16);
    hv.w = (unsigned)f2h(a1.z) | ((unsigned)f2h(a1.w) << 16);
    G.h2[(size_t)n * NH + hd] = hv;
  }
}

// One block per bucket. LDS counting sort with key (dst_local,seg): emits
// per-(node,seg) ABSOLUTE csr offsets offs2[] and a csr that is dst-major,
// seg-sorted, living in the bucket's [b*BSTRIDE, b*BSTRIDE+count) window.
__global__ __launch_bounds__(256) void k_scat2(GT t) {
  const GP G = t.g[blockIdx.z];
  const int b = blockIdx.x;
  const int d0 = b << 8;
  __shared__ int cnt[256 * SPAD];   // 17.4 KB (counts, then cursors)
  __shared__ int ssum[256];
  const int tid = threadIdx.x;
  const int estart = b * BSTRIDE;
  const int eend = estart + G.bcursor[b];
  for (int i = tid; i < 256 * SPAD; i += 256) cnt[i] = 0;
  __syncthreads();
  for (int e = estart + tid; e < eend; e += 256) {
    unsigned p = G.pairs[e];
    int key = (int)((p >> 16) * SPAD + ((p & 0xFFFFu) >> 12));
    atomicAdd(&cnt[key], 1);
  }
  __syncthreads();
  // scan: thread t owns keys t*SPAD .. t*SPAD+15 (= dst_local t, all segs)
  int local[NSEG];
  int sum = 0;
  #pragma unroll
  for (int i = 0; i < NSEG; ++i) { local[i] = sum; sum += cnt[tid * SPAD + i]; }
  ssum[tid] = sum;
  __syncthreads();
  int run = sum;
  for (int off = 1; off < 256; off <<= 1) {
    int u = (tid >= off) ? ssum[tid - off] : 0;
    __syncthreads();
    run += u;
    ssum[tid] = run;
    __syncthreads();
  }
  const int texcl = run - sum;
  int* o2 = G.offs2 + ((size_t)d0 << 4);
  #pragma unroll
  for (int i = 0; i < NSEG; ++i) {
    int v = estart + texcl + local[i];
    cnt[tid * SPAD + i] = v;     // counts dead; reuse as cursors
    o2[tid * NSEG + i] = v;
  }
  __syncthreads();
  for (int e = estart + tid; e < eend; e += 256) {
    unsigned p = G.pairs[e];
    int key = (int)((p >> 16) * SPAD + ((p & 0xFFFFu) >> 12));
    int pos = atomicAdd(&cnt[key], 1);
    G.csr[pos] = (int)(p & 0xFFFFu);
  }
}

// gather aggregation: thread (dst,head). Barrier every 4 src-segments;
// 8/4/1-tier batched loads for memory-level parallelism.
__global__ __launch_bounds__(256) void k_agg(GT t) {
  const GP G = t.g[blockIdx.z];
  const int gid = blockIdx.x * 256 + threadIdx.x;
  const bool active = (gid < NN * NH);
  int n = 0, head = 0;
  if (active) { n = gid / NH; head = gid - n * NH; }
  float denom = 0.f;
  float4 acc0 = make_float4(0.f, 0.f, 0.f, 0.f);
  float4 acc1 = make_float4(0.f, 0.f, 0.f, 0.f);
  float ad_n = 0.f;
  int gb[5] = {0, 0, 0, 0, 0};
  if (active) {
    ad_n = G.a_d[n * NH + head];
    const int* o2 = G.offs2 + ((size_t)n << 4);
    gb[0] = o2[0]; gb[1] = o2[4]; gb[2] = o2[8]; gb[3] = o2[12]; gb[4] = o2[13];
    float sl = h2f(G.as2[n * NH + head]) + ad_n;
    sl = (sl > 0.f) ? sl : NEG * sl;
    float wl = __expf(sl);
    uint4 hs = G.h2[(size_t)n * NH + head];
    denom = wl;
    acc0.x = wl * hlo(hs.x); acc0.y = wl * hhi(hs.x);
    acc0.z = wl * hlo(hs.y); acc0.w = wl * hhi(hs.y);
    acc1.x = wl * hlo(hs.z); acc1.y = wl * hhi(hs.z);
    acc1.z = wl * hlo(hs.w); acc1.w = wl * hhi(hs.w);
  }
  #pragma unroll
  for (int g = 0; g < 4; ++g) {
    int e = gb[g];
    const int en = gb[g + 1];
    for (; e + 8 <= en; e += 8) {
      int s[8];
      #pragma unroll
      for (int i = 0; i < 8; ++i) s[i] = G.csr[e + i];
      unsigned short u[8];
      #pragma unroll
      for (int i = 0; i < 8; ++i) u[i] = G.as2[s[i] * NH + head];
      uint4 v[8];
      #pragma unroll
      for (int i = 0; i < 8; ++i) v[i] = G.h2[(size_t)s[i] * NH + head];
      #pragma unroll
      for (int i = 0; i < 8; ++i) {
        float sc = h2f(u[i]) + ad_n;
        sc = (sc > 0.f) ? sc : NEG * sc;
        float w = __expf(sc);
        denom += w;
        acc0.x = fmaf(w, hlo(v[i].x), acc0.x); acc0.y = fmaf(w, hhi(v[i].x), acc0.y);
        acc0.z = fmaf(w, hlo(v[i].y), acc0.z); acc0.w = fmaf(w, hhi(v[i].y), acc0.w);
        acc1.x = fmaf(w, hlo(v[i].z), acc1.x); acc1.y = fmaf(w, hhi(v[i].z), acc1.y);
        acc1.z = fmaf(w, hlo(v[i].w), acc1.z); acc1.w = fmaf(w, hhi(v[i].w), acc1.w);
      }
    }
    if (e + 4 <= en) {
      int s[4];
      #pragma unroll
      for (int i = 0; i < 4; ++i) s[i] = G.csr[e + i];
      unsigned short u[4];
      #pragma unroll
      for (int i = 0; i < 4; ++i) u[i] = G.as2[s[i] * NH + head];
      uint4 v[4];
      #pragma unroll
      for (int i = 0; i < 4; ++i) v[i] = G.h2[(size_t)s[i] * NH + head];
      #pragma unroll
      for (int i = 0; i < 4; ++i) {
        float sc = h2f(u[i]) + ad_n;
        sc = (sc > 0.f) ? sc : NEG * sc;
        float w = __expf(sc);
        denom += w;
        acc0.x = fmaf(w, hlo(v[i].x), acc0.x); acc0.y = fmaf(w, hhi(v[i].x), acc0.y);
        acc0.z = fmaf(w, hlo(v[i].y), acc0.z); acc0.w = fmaf(w, hhi(v[i].y), acc0.w);
        acc1.x = fmaf(w, hlo(v[i].z), acc1.x); acc1.y = fmaf(w, hhi(v[i].z), acc1.y);
        acc1.z = fmaf(w, hlo(v[i].w), acc1.z); acc1.w = fmaf(w, hhi(v[i].w), acc1.w);
      }
      e += 4;
    }
    for (; e < en; ++e) {
      int src = G.csr[e];
      float sc = h2f(G.as2[src * NH + head]) + ad_n;
      sc = (sc > 0.f) ? sc : NEG * sc;
      float w = __expf(sc);
      uint4 hv = G.h2[(size_t)src * NH + head];
      denom += w;
      acc0.x = fmaf(w, hlo(hv.x), acc0.x); acc0.y = fmaf(w, hhi(hv.x), acc0.y);
      acc0.z = fmaf(w, hlo(hv.y), acc0.z); acc0.w = fmaf(w, hhi(hv.y), acc0.w);
      acc1.x = fmaf(w, hlo(hv.z), acc1.x); acc1.y = fmaf(w, hhi(hv.z), acc1.y);
      acc1.z = fmaf(w, hlo(hv.w), acc1.z); acc1.w = fmaf(w, hhi(hv.w), acc1.w);
    }
    __syncthreads();
  }
  if (!active) return;
  float inv = 1.f / (denom + 1e-16f);
  const float* bp = G.b + head * NC;
  float4 o0, o1;
  o0.x = acc0.x * inv + bp[0]; o0.y = acc0.y * inv + bp[1];
  o0.z = acc0.z * inv + bp[2]; o0.w = acc0.w * inv + bp[3];
  o1.x = acc1.x * inv + bp[4]; o1.y = acc1.y * inv + bp[5];
  o1.z = acc1.z * inv + bp[6]; o1.w = acc1.w * inv + bp[7];
  float4* op = (float4*)(G.out + (size_t)n * HCH + head * NC);
  op[0] = o0; op[1] = o1;
}

// relu(concat) @ fnn_W + fnn_b -> softmax(2). One wave per node.
__global__ __launch_bounds__(256) void k_fnn(const float* __restrict__ o1,
                                             const float* __restrict__ o2,
                                             const float* __restrict__ o3,
                                             const float* __restrict__ fw,
                                             const float* __restrict__ fb,
                                             float* __restrict__ out) {
  const int tid = blockIdx.x * 256 + threadIdx.x;
  const int n = tid >> 6;
  const int lane = tid & 63;
  if (n >= NN) return;
  float acc0 = 0.f, acc1 = 0.f;
  for (int j = lane; j < 3 * HCH; j += 64) {
    const int g = j / HCH;
    const int c = j - g * HCH;
    const float* og = (g == 0) ? o1 : (g == 1) ? o2 : o3;
    float v = og[(size_t)n * HCH + c];
    v = v > 0.f ? v : 0.f;
    acc0 = fmaf(v, fw[2 * j], acc0);
    acc1 = fmaf(v, fw[2 * j + 1], acc1);
  }
  #pragma unroll
  for (int off = 32; off > 0; off >>= 1) {
    acc0 += __shfl_down(acc0, off, 64);
    acc1 += __shfl_down(acc1, off, 64);
  }
  if (lane == 0) {
    float l0 = acc0 + fb[0], l1 = acc1 + fb[1];
    float m = fmaxf(l0, l1);
    float e0 = __expf(l0 - m), e1 = __expf(l1 - m);
    float inv = 1.f / (e0 + e1);
    out[(size_t)n * 2] = e0 * inv;
    out[(size_t)n * 2 + 1] = e1 * inv;
  }
}

extern "C" void kernel_launch(void* const* d_in, const int* in_sizes, int n_in,
                              void* d_out, int out_size, void* d_ws, size_t ws_size,
                              hipStream_t stream) {
  (void)in_sizes; (void)n_in; (void)out_size; (void)ws_size;
  GT t;
  char* w = (char*)d_ws;
  size_t off = 0;
  auto carve = [&](size_t bytes) -> void* {
    void* p = w + off;
    off = (off + bytes + 255) & ~(size_t)255;
    return p;
  };
  int* bc_all = (int*)carve(3 * 256 * 4);   // 3 graphs' bcursor, contiguous
  for (int g = 0; g < 3; ++g) {
    GP& G = t.g[g];
    G.x  = (const float*)d_in[6 * g + 0];
    G.ei = (const int*)d_in[6 * g + 1];     // harness stores int64 inputs as int32
    G.W  = (const float*)d_in[6 * g + 2];
    G.as = (const float*)d_in[6 * g + 3];
    G.ad = (const float*)d_in[6 * g + 4];
    G.b  = (const float*)d_in[6 * g + 5];
    G.bcursor = bc_all + g * 256;
    G.h2   = (uint4*)carve((size_t)NN * NH * 16);
    G.as2  = (unsigned short*)carve((size_t)NN * NH * 2);
    G.a_d  = (float*)carve((size_t)NN * NH * 4);
    G.out  = (float*)carve((size_t)NN * HCH * 4);
    G.offs2 = (int*)carve((size_t)NBUCK * 256 * NSEG * 4);
    G.pairs = (unsigned int*)carve((size_t)NBUCK * BSTRIDE * 4);
    G.csr   = (int*)carve((size_t)NBUCK * BSTRIDE * 4);
  }
  const float* fw = (const float*)d_in[18];
  const float* fb = (const float*)d_in[19];
  float* outp = (float*)d_out;

  dim3 b256(256, 1, 1);
  hipMemsetAsync(bc_all, 0, 3 * 256 * 4, stream);
  k_gemm_bin<<<dim3(GEMMB + BINB, 1, 3), b256, 0, stream>>>(t);
  k_scat2   <<<dim3(NBUCK, 1, 3), b256, 0, stream>>>(t);
  k_agg     <<<dim3((NN * NH + 255) / 256, 1, 3), b256, 0, stream>>>(t);
  k_fnn     <<<(NN * 64 + 255) / 256, b256, 0, stream>>>(t.g[0].out, t.g[1].out, t.g[2].out, fw, fb, outp);
}

// Round 14
// 437.992 us; speedup vs baseline: 1.3055x; 1.0406x over previous
//
#include <hip/hip_runtime.h>
#include <hip/hip_fp16.h>

#define NN 50000
#define NE 1600000
#define DD 128
#define NH 9
#define NC 8
#define HCH 72
#define NEG 0.2f
#define NBUCK 196      // ceil(50000/256), 256 dst nodes per bucket
#define NSEG 16        // src segments of 4096 nodes (only 0..12 non-empty)
#define SPAD 17        // padded seg stride in k_scat2 LDS (bank-conflict fix)
#define EPB 8          // edges per thread in bin part
#define BCH (256*EPB)  // 2048 edges per bin block
#define BSTRIDE 10240  // fixed per-bucket capacity (mean 8192, sigma 90 -> +22 sigma)
#define GEMMB 586      // ceil(NN*3/256) gemm blocks
#define BINB ((NE + BCH - 1) / BCH)  // 782 bin blocks

__device__ __forceinline__ unsigned short f2h(float f) {
  return __half_as_ushort(__float2half_rn(f));
}
__device__ __forceinline__ float h2f(unsigned short u) {
  return __half2float(__ushort_as_half(u));
}
__device__ __forceinline__ float hlo(unsigned u) {
  return __half2float(__ushort_as_half((unsigned short)(u & 0xFFFFu)));
}
__device__ __forceinline__ float hhi(unsigned u) {
  return __half2float(__ushort_as_half((unsigned short)(u >> 16)));
}

struct GP {
  const float* x; const int* ei; const float* W;
  const float* as; const float* ad; const float* b;
  uint4* h2;                // [NN*9] uint4: 8 fp16 channels per (node,head)
  unsigned short* as2;      // [NN*9] fp16 src-attention scores
  float* a_d; float* out;
  int* offs2;               // [NBUCK*256*16] per-(node,seg) absolute csr offsets
  int* bcursor;             // [NBUCK] bucket fill counts (atomic)
  unsigned int* pairs;      // [NBUCK*BSTRIDE] strided bucket runs
  int* csr;                 // [NBUCK*BSTRIDE]
};
struct GT { GP g[3]; };

// Fat kernel. Blocks [0,GEMMB): h = x@W, one thread per (node, head-triple),
// 24 channels in registers, W in LDS. Blocks [GEMMB,GEMMB+BINB): bin edges
// into fixed-stride bucket runs (atomicAdd reservation, no histogram/scan).
__global__ __launch_bounds__(256) void k_gemm_bin(GT t) {
  const GP G = t.g[blockIdx.z];
  __shared__ float Wl[DD * HCH];   // 36 KB
  const int tid = threadIdx.x;

  if (blockIdx.x >= GEMMB) {
    // ---- bin part (aliases Wl as int scratch) ----
    int* lh    = (int*)Wl;         // 256 ints
    int* lbase = lh + 256;
    int* lcur  = lbase + 256;
    const int e0 = (blockIdx.x - GEMMB) * BCH;
    for (int i = tid; i < NBUCK; i += 256) lh[i] = 0;
    __syncthreads();
    int dsts[EPB], srcs[EPB];
    #pragma unroll
    for (int k = 0; k < EPB; ++k) {
      const int e = e0 + k * 256 + tid;
      if (e < NE) {
        dsts[k] = G.ei[NE + e];
        srcs[k] = G.ei[e];
        atomicAdd(&lh[dsts[k] >> 8], 1);
      } else dsts[k] = -1;
    }
    __syncthreads();
    for (int i = tid; i < NBUCK; i += 256) {
      int c = lh[i];
      lbase[i] = c ? atomicAdd(&G.bcursor[i], c) : 0;
      lcur[i] = 0;
    }
    __syncthreads();
    #pragma unroll
    for (int k = 0; k < EPB; ++k) {
      if (dsts[k] >= 0) {
        int b = dsts[k] >> 8;
        int pos = lbase[b] + atomicAdd(&lcur[b], 1);
        if (pos < BSTRIDE)   // overflow guard (+22 sigma, effectively never)
          G.pairs[(size_t)b * BSTRIDE + pos] =
              (unsigned)srcs[k] | ((unsigned)(dsts[k] & 255) << 16);
      }
    }
    return;
  }

  // ---- gemm part ----
  {
    const float4* Wg = (const float4*)G.W;
    float4* Wd = (float4*)Wl;
    #pragma unroll
    for (int i = 0; i < 9; ++i) Wd[tid + 256 * i] = Wg[tid + 256 * i];  // 2304
  }
  const int gid = blockIdx.x * 256 + tid;
  __syncthreads();
  if (gid >= NN * 3) return;
  const int n  = gid / 3;
  const int g3 = gid - n * 3;            // heads 3*g3 .. 3*g3+2
  float4 acc[6];
  #pragma unroll
  for (int i = 0; i < 6; ++i) acc[i] = make_float4(0.f, 0.f, 0.f, 0.f);
  const float4* x4 = (const float4*)(G.x + (size_t)n * DD);
  const float* wb = Wl + g3 * 24;

  for (int k4 = 0; k4 < DD / 4; ++k4) {
    const float4 xv = x4[k4];
    #pragma unroll
    for (int kk = 0; kk < 4; ++kk) {
      const float xk = (kk == 0) ? xv.x : (kk == 1) ? xv.y : (kk == 2) ? xv.z : xv.w;
      const float4* wr = (const float4*)(wb + (k4 * 4 + kk) * HCH);
      #pragma unroll
      for (int c = 0; c < 6; ++c) {
        float4 wv = wr[c];     // 3 distinct lane-addresses, banks {0,24,16}
        acc[c].x = fmaf(xk, wv.x, acc[c].x);
        acc[c].y = fmaf(xk, wv.y, acc[c].y);
        acc[c].z = fmaf(xk, wv.z, acc[c].z);
        acc[c].w = fmaf(xk, wv.w, acc[c].w);
      }
    }
  }

  #pragma unroll
  for (int j = 0; j < 3; ++j) {
    const int hd = 3 * g3 + j;
    const float4 a0 = acc[2 * j];
    const float4 a1 = acc[2 * j + 1];
    const float4 As0 = *(const float4*)(G.as + hd * NC);
    const float4 As1 = *(const float4*)(G.as + hd * NC + 4);
    const float4 Ad0 = *(const float4*)(G.ad + hd * NC);
    const float4 Ad1 = *(const float4*)(G.ad + hd * NC + 4);
    float ssrc = a0.x*As0.x + a0.y*As0.y + a0.z*As0.z + a0.w*As0.w
               + a1.x*As1.x + a1.y*As1.y + a1.z*As1.z + a1.w*As1.w;
    float sdst = a0.x*Ad0.x + a0.y*Ad0.y + a0.z*Ad0.z + a0.w*Ad0.w
               + a1.x*Ad1.x + a1.y*Ad1.y + a1.z*Ad1.z + a1.w*Ad1.w;
    G.as2[n * NH + hd] = f2h(ssrc);
    G.a_d[n * NH + hd] = sdst;
    uint4 hv;
    hv.x = (unsigned)f2h(a0.x) | ((unsigned)f2h(a0.y) << 16);
    hv.y = (unsigned)f2h(a0.z) | ((unsigned)f2h(a0.w) << 16);
    hv.z = (unsigned)f2h(a1.x) | ((unsigned)f2h(a1.y) << 16);
    hv.w = (unsigned)f2h(a1.z) | ((unsigned)f2h(a1.w) << 16);
    G.h2[(size_t)n * NH + hd] = hv;
  }
}

// One block per bucket. LDS counting sort with key (dst_local,seg): emits
// per-(node,seg) ABSOLUTE csr offsets offs2[] and a seg-sorted dst-major csr.
__global__ __launch_bounds__(256) void k_scat2(GT t) {
  const GP G = t.g[blockIdx.z];
  const int b = blockIdx.x;
  const int d0 = b << 8;
  __shared__ int cnt[256 * SPAD];   // 17.4 KB (counts, then cursors)
  __shared__ int ssum[256];
  const int tid = threadIdx.x;
  const int estart = b * BSTRIDE;
  const int eend = estart + G.bcursor[b];
  for (int i = tid; i < 256 * SPAD; i += 256) cnt[i] = 0;
  __syncthreads();
  for (int e = estart + tid; e < eend; e += 256) {
    unsigned p = G.pairs[e];
    int key = (int)((p >> 16) * SPAD + ((p & 0xFFFFu) >> 12));
    atomicAdd(&cnt[key], 1);
  }
  __syncthreads();
  int local[NSEG];
  int sum = 0;
  #pragma unroll
  for (int i = 0; i < NSEG; ++i) { local[i] = sum; sum += cnt[tid * SPAD + i]; }
  ssum[tid] = sum;
  __syncthreads();
  int run = sum;
  for (int off = 1; off < 256; off <<= 1) {
    int u = (tid >= off) ? ssum[tid - off] : 0;
    __syncthreads();
    run += u;
    ssum[tid] = run;
    __syncthreads();
  }
  const int texcl = run - sum;
  int* o2 = G.offs2 + ((size_t)d0 << 4);
  #pragma unroll
  for (int i = 0; i < NSEG; ++i) {
    int v = estart + texcl + local[i];
    cnt[tid * SPAD + i] = v;     // counts dead; reuse as cursors
    o2[tid * NSEG + i] = v;
  }
  __syncthreads();
  for (int e = estart + tid; e < eend; e += 256) {
    unsigned p = G.pairs[e];
    int key = (int)((p >> 16) * SPAD + ((p & 0xFFFFu) >> 12));
    int pos = atomicAdd(&cnt[key], 1);
    G.csr[pos] = (int)(p & 0xFFFFu);
  }
}

// gather aggregation (R10-proven form): thread (dst,head), barrier every
// 4 src-segments, 4-edge batched loads. One graph per dispatch (visibility).
__global__ __launch_bounds__(256) void k_agg(GP G) {
  const int gid = blockIdx.x * 256 + threadIdx.x;
  const bool active = (gid < NN * NH);
  int n = 0, head = 0;
  if (active) { n = gid / NH; head = gid - n * NH; }
  float denom = 0.f;
  float4 acc0 = make_float4(0.f, 0.f, 0.f, 0.f);
  float4 acc1 = make_float4(0.f, 0.f, 0.f, 0.f);
  float ad_n = 0.f;
  int gb[5] = {0, 0, 0, 0, 0};
  if (active) {
    ad_n = G.a_d[n * NH + head];
    const int* o2 = G.offs2 + ((size_t)n << 4);
    gb[0] = o2[0]; gb[1] = o2[4]; gb[2] = o2[8]; gb[3] = o2[12]; gb[4] = o2[13];
    float sl = h2f(G.as2[n * NH + head]) + ad_n;
    sl = (sl > 0.f) ? sl : NEG * sl;
    float wl = __expf(sl);
    uint4 hs = G.h2[(size_t)n * NH + head];
    denom = wl;
    acc0.x = wl * hlo(hs.x); acc0.y = wl * hhi(hs.x);
    acc0.z = wl * hlo(hs.y); acc0.w = wl * hhi(hs.y);
    acc1.x = wl * hlo(hs.z); acc1.y = wl * hhi(hs.z);
    acc1.z = wl * hlo(hs.w); acc1.w = wl * hhi(hs.w);
  }
  #pragma unroll
  for (int g = 0; g < 4; ++g) {
    int e = gb[g];
    const int en = gb[g + 1];
    for (; e + 4 <= en; e += 4) {
      int s0 = G.csr[e];
      int s1 = G.csr[e + 1];
      int s2 = G.csr[e + 2];
      int s3 = G.csr[e + 3];
      unsigned short u0 = G.as2[s0 * NH + head];
      unsigned short u1 = G.as2[s1 * NH + head];
      unsigned short u2 = G.as2[s2 * NH + head];
      unsigned short u3 = G.as2[s3 * NH + head];
      uint4 v0 = G.h2[(size_t)s0 * NH + head];
      uint4 v1 = G.h2[(size_t)s1 * NH + head];
      uint4 v2 = G.h2[(size_t)s2 * NH + head];
      uint4 v3 = G.h2[(size_t)s3 * NH + head];
      float t0 = h2f(u0) + ad_n;
      float t1 = h2f(u1) + ad_n;
      float t2 = h2f(u2) + ad_n;
      float t3 = h2f(u3) + ad_n;
      t0 = (t0 > 0.f) ? t0 : NEG * t0;
      t1 = (t1 > 0.f) ? t1 : NEG * t1;
      t2 = (t2 > 0.f) ? t2 : NEG * t2;
      t3 = (t3 > 0.f) ? t3 : NEG * t3;
      float w0 = __expf(t0);
      float w1 = __expf(t1);
      float w2 = __expf(t2);
      float w3 = __expf(t3);
      denom += (w0 + w1) + (w2 + w3);
      acc0.x = fmaf(w0, hlo(v0.x), acc0.x); acc0.y = fmaf(w0, hhi(v0.x), acc0.y);
      acc0.z = fmaf(w0, hlo(v0.y), acc0.z); acc0.w = fmaf(w0, hhi(v0.y), acc0.w);
      acc1.x = fmaf(w0, hlo(v0.z), acc1.x); acc1.y = fmaf(w0, hhi(v0.z), acc1.y);
      acc1.z = fmaf(w0, hlo(v0.w), acc1.z); acc1.w = fmaf(w0, hhi(v0.w), acc1.w);
      acc0.x = fmaf(w1, hlo(v1.x), acc0.x); acc0.y = fmaf(w1, hhi(v1.x), acc0.y);
      acc0.z = fmaf(w1, hlo(v1.y), acc0.z); acc0.w = fmaf(w1, hhi(v1.y), acc0.w);
      acc1.x = fmaf(w1, hlo(v1.z), acc1.x); acc1.y = fmaf(w1, hhi(v1.z), acc1.y);
      acc1.z = fmaf(w1, hlo(v1.w), acc1.z); acc1.w = fmaf(w1, hhi(v1.w), acc1.w);
      acc0.x = fmaf(w2, hlo(v2.x), acc0.x); acc0.y = fmaf(w2, hhi(v2.x), acc0.y);
      acc0.z = fmaf(w2, hlo(v2.y), acc0.z); acc0.w = fmaf(w2, hhi(v2.y), acc0.w);
      acc1.x = fmaf(w2, hlo(v2.z), acc1.x); acc1.y = fmaf(w2, hhi(v2.z), acc1.y);
      acc1.z = fmaf(w2, hlo(v2.w), acc1.z); acc1.w = fmaf(w2, hhi(v2.w), acc1.w);
      acc0.x = fmaf(w3, hlo(v3.x), acc0.x); acc0.y = fmaf(w3, hhi(v3.x), acc0.y);
      acc0.z = fmaf(w3, hlo(v3.y), acc0.z); acc0.w = fmaf(w3, hhi(v3.y), acc0.w);
      acc1.x = fmaf(w3, hlo(v3.z), acc1.x); acc1.y = fmaf(w3, hhi(v3.z), acc1.y);
      acc1.z = fmaf(w3, hlo(v3.w), acc1.z); acc1.w = fmaf(w3, hhi(v3.w), acc1.w);
    }
    for (; e < en; ++e) {
      int src = G.csr[e];
      float sc = h2f(G.as2[src * NH + head]) + ad_n;
      sc = (sc > 0.f) ? sc : NEG * sc;
      float w = __expf(sc);
      uint4 hv = G.h2[(size_t)src * NH + head];
      denom += w;
      acc0.x = fmaf(w, hlo(hv.x), acc0.x); acc0.y = fmaf(w, hhi(hv.x), acc0.y);
      acc0.z = fmaf(w, hlo(hv.y), acc0.z); acc0.w = fmaf(w, hhi(hv.y), acc0.w);
      acc1.x = fmaf(w, hlo(hv.z), acc1.x); acc1.y = fmaf(w, hhi(hv.z), acc1.y);
      acc1.z = fmaf(w, hlo(hv.w), acc1.z); acc1.w = fmaf(w, hhi(hv.w), acc1.w);
    }
    __syncthreads();
  }
  if (!active) return;
  float inv = 1.f / (denom + 1e-16f);
  const float* bp = G.b + head * NC;
  float4 o0, o1;
  o0.x = acc0.x * inv + bp[0]; o0.y = acc0.y * inv + bp[1];
  o0.z = acc0.z * inv + bp[2]; o0.w = acc0.w * inv + bp[3];
  o1.x = acc1.x * inv + bp[4]; o1.y = acc1.y * inv + bp[5];
  o1.z = acc1.z * inv + bp[6]; o1.w = acc1.w * inv + bp[7];
  float4* op = (float4*)(G.out + (size_t)n * HCH + head * NC);
  op[0] = o0; op[1] = o1;
}

// relu(concat) @ fnn_W + fnn_b -> softmax(2). One wave per node.
__global__ __launch_bounds__(256) void k_fnn(const float* __restrict__ o1,
                                             const float* __restrict__ o2,
                                             const float* __restrict__ o3,
                                             const float* __restrict__ fw,
                                             const float* __restrict__ fb,
                                             float* __restrict__ out) {
  const int tid = blockIdx.x * 256 + threadIdx.x;
  const int n = tid >> 6;
  const int lane = tid & 63;
  if (n >= NN) return;
  float acc0 = 0.f, acc1 = 0.f;
  for (int j = lane; j < 3 * HCH; j += 64) {
    const int g = j / HCH;
    const int c = j - g * HCH;
    const float* og = (g == 0) ? o1 : (g == 1) ? o2 : o3;
    float v = og[(size_t)n * HCH + c];
    v = v > 0.f ? v : 0.f;
    acc0 = fmaf(v, fw[2 * j], acc0);
    acc1 = fmaf(v, fw[2 * j + 1], acc1);
  }
  #pragma unroll
  for (int off = 32; off > 0; off >>= 1) {
    acc0 += __shfl_down(acc0, off, 64);
    acc1 += __shfl_down(acc1, off, 64);
  }
  if (lane == 0) {
    float l0 = acc0 + fb[0], l1 = acc1 + fb[1];
    float m = fmaxf(l0, l1);
    float e0 = __expf(l0 - m), e1 = __expf(l1 - m);
    float inv = 1.f / (e0 + e1);
    out[(size_t)n * 2] = e0 * inv;
    out[(size_t)n * 2 + 1] = e1 * inv;
  }
}

extern "C" void kernel_launch(void* const* d_in, const int* in_sizes, int n_in,
                              void* d_out, int out_size, void* d_ws, size_t ws_size,
                              hipStream_t stream) {
  (void)in_sizes; (void)n_in; (void)out_size; (void)ws_size;
  GT t;
  char* w = (char*)d_ws;
  size_t off = 0;
  auto carve = [&](size_t bytes) -> void* {
    void* p = w + off;
    off = (off + bytes + 255) & ~(size_t)255;
    return p;
  };
  int* bc_all = (int*)carve(3 * 256 * 4);   // 3 graphs' bcursor, contiguous
  for (int g = 0; g < 3; ++g) {
    GP& G = t.g[g];
    G.x  = (const float*)d_in[6 * g + 0];
    G.ei = (const int*)d_in[6 * g + 1];     // harness stores int64 inputs as int32
    G.W  = (const float*)d_in[6 * g + 2];
    G.as = (const float*)d_in[6 * g + 3];
    G.ad = (const float*)d_in[6 * g + 4];
    G.b  = (const float*)d_in[6 * g + 5];
    G.bcursor = bc_all + g * 256;
    G.h2   = (uint4*)carve((size_t)NN * NH * 16);
    G.as2  = (unsigned short*)carve((size_t)NN * NH * 2);
    G.a_d  = (float*)carve((size_t)NN * NH * 4);
    G.out  = (float*)carve((size_t)NN * HCH * 4);
    G.offs2 = (int*)carve((size_t)NBUCK * 256 * NSEG * 4);
    G.pairs = (unsigned int*)carve((size_t)NBUCK * BSTRIDE * 4);
    G.csr   = (int*)carve((size_t)NBUCK * BSTRIDE * 4);
  }
  const float* fw = (const float*)d_in[18];
  const float* fb = (const float*)d_in[19];
  float* outp = (float*)d_out;

  dim3 b256(256, 1, 1);
  hipMemsetAsync(bc_all, 0, 3 * 256 * 4, stream);
  k_gemm_bin<<<dim3(GEMMB + BINB, 1, 3), b256, 0, stream>>>(t);
  k_scat2   <<<dim3(NBUCK, 1, 3), b256, 0, stream>>>(t);
  for (int g = 0; g < 3; ++g)
    k_agg   <<<dim3((NN * NH + 255) / 256, 1, 1), b256, 0, stream>>>(t.g[g]);
  k_fnn     <<<(NN * 64 + 255) / 256, b256, 0, stream>>>(t.g[0].out, t.g[1].out, t.g[2].out, fw, fb, outp);
}